// Round 4
// baseline (2528.801 us; speedup 1.0000x reference)
//
#include <hip/hip_runtime.h>
#include <hip/hip_bf16.h>
#include <math.h>

#define B_ 2
#define L_ 4096
#define D_ 1024
#define DIN 2048
#define DPROJ 4160
#define CONVD 2080
#define H_ 32
#define P_ 64
#define N_ 16
#define K_ 4
#define M_ROWS (B_*L_)

typedef __bf16 bf16_8 __attribute__((ext_vector_type(8)));
typedef float f32x4 __attribute__((ext_vector_type(4)));

// ---------------- RMSNorm (fp32 in, bf16 out) ----------------
template<typename TI>
__global__ __launch_bounds__(256) void rms_kernel(const TI* __restrict__ x,
        const float* __restrict__ w, __bf16* __restrict__ out) {
    int row = blockIdx.x;
    int tid = threadIdx.x;
    const TI* xr = x + (size_t)row * D_;
    float v[4];
    float ss = 0.f;
#pragma unroll
    for (int i = 0; i < 4; i++) {
        v[i] = (float)xr[tid*4 + i];
        ss += v[i]*v[i];
    }
#pragma unroll
    for (int off = 32; off >= 1; off >>= 1) ss += __shfl_xor(ss, off, 64);
    __shared__ float sred[4];
    int wave = tid >> 6;
    if ((tid & 63) == 0) sred[wave] = ss;
    __syncthreads();
    ss = sred[0] + sred[1] + sred[2] + sred[3];
    float scale = rsqrtf(ss * (1.f/(float)D_) + 1e-6f);
#pragma unroll
    for (int i = 0; i < 4; i++)
        out[(size_t)row*D_ + tid*4 + i] = (__bf16)(v[i] * scale * w[tid*4 + i]);
}

// ---------------- GEMM: C = A(MxK,bf16) @ W(NxK,fp32->bf16)^T ----------------
// EPI 0: store bf16
// EPI 2: acc + bias + fp32 residual -> fp32 store
// EPI 3: gelu_tanh(acc + bias) -> bf16
// EPI 4: acc + bias + fp32 residual -> fp32 store (final output)
#define BM 128
#define BN 128
#define BK 32
#define BKP 40

template<int EPI, typename TW>
__global__ __launch_bounds__(256) void gemm_kernel(
    const __bf16* __restrict__ A, const TW* __restrict__ W,
    void* __restrict__ Cout, const float* __restrict__ bias,
    const float* __restrict__ resid, int M, int N, int K)
{
    __shared__ __attribute__((aligned(16))) __bf16 As[BM][BKP];
    __shared__ __attribute__((aligned(16))) __bf16 Bs[BN][BKP];
    int tid = threadIdx.x;
    int lane = tid & 63, wave = tid >> 6;
    int wm = wave >> 1, wn = wave & 1;
    int quad = lane >> 4, l16 = lane & 15;
    int bm0 = blockIdx.y * BM, bn0 = blockIdx.x * BN;

    f32x4 acc[4][4] = {};

    for (int kk = 0; kk < K; kk += BK) {
#pragma unroll
        for (int c = 0; c < 2; c++) {
            int chunk = tid + c*256;
            int row = chunk >> 2;
            int col = (chunk & 3) << 3;
            *(uint4*)&As[row][col] = *(const uint4*)(A + (size_t)(bm0+row)*K + kk + col);
            int nr = bn0 + row;
            if constexpr (sizeof(TW) == 2) {
                uint4 bv = make_uint4(0u,0u,0u,0u);
                if (nr < N) bv = *(const uint4*)((const __bf16*)W + (size_t)nr*K + kk + col);
                *(uint4*)&Bs[row][col] = bv;
            } else {
                bf16_8 bv;
#pragma unroll
                for (int q = 0; q < 8; q++) bv[q] = (__bf16)0.f;
                if (nr < N) {
                    const float* wp = (const float*)W + (size_t)nr*K + kk + col;
                    float4 f0 = *(const float4*)wp;
                    float4 f1 = *(const float4*)(wp + 4);
                    bv[0]=(__bf16)f0.x; bv[1]=(__bf16)f0.y; bv[2]=(__bf16)f0.z; bv[3]=(__bf16)f0.w;
                    bv[4]=(__bf16)f1.x; bv[5]=(__bf16)f1.y; bv[6]=(__bf16)f1.z; bv[7]=(__bf16)f1.w;
                }
                *(bf16_8*)&Bs[row][col] = bv;
            }
        }
        __syncthreads();
        bf16_8 af[4], bfr[4];
#pragma unroll
        for (int i = 0; i < 4; i++) {
            af[i]  = *(const bf16_8*)&As[wm*64 + i*16 + l16][quad*8];
            bfr[i] = *(const bf16_8*)&Bs[wn*64 + i*16 + l16][quad*8];
        }
#pragma unroll
        for (int mi = 0; mi < 4; mi++)
#pragma unroll
            for (int ni = 0; ni < 4; ni++)
                acc[mi][ni] = __builtin_amdgcn_mfma_f32_16x16x32_bf16(af[mi], bfr[ni], acc[mi][ni], 0, 0, 0);
        __syncthreads();
    }

#pragma unroll
    for (int mi = 0; mi < 4; mi++) {
        int mbase = bm0 + wm*64 + mi*16 + quad*4;
#pragma unroll
        for (int ni = 0; ni < 4; ni++) {
            int n = bn0 + wn*64 + ni*16 + l16;
            if (n < N) {
#pragma unroll
                for (int r = 0; r < 4; r++) {
                    size_t idx = (size_t)(mbase + r)*N + n;
                    float v = acc[mi][ni][r];
                    if constexpr (EPI == 0) {
                        ((__bf16*)Cout)[idx] = (__bf16)v;
                    } else if constexpr (EPI == 2) {
                        v += bias[n] + resid[idx];
                        ((float*)Cout)[idx] = v;
                    } else if constexpr (EPI == 3) {
                        v += bias[n];
                        float g = 0.5f*v*(1.f + tanhf(0.7978845608f*(v + 0.044715f*v*v*v)));
                        ((__bf16*)Cout)[idx] = (__bf16)g;
                    } else if constexpr (EPI == 4) {
                        v += bias[n] + resid[idx];
                        ((float*)Cout)[idx] = v;   // final output is fp32
                    }
                }
            }
        }
    }
}

// ---------------- depthwise causal conv (K=4) + SiLU ----------------
__global__ __launch_bounds__(256) void conv_kernel(
    const __bf16* __restrict__ proj, const float* __restrict__ cw,
    const float* __restrict__ cb, __bf16* __restrict__ u_out,
    float* __restrict__ bc_out)
{
    int idx = blockIdx.x*256 + threadIdx.x;
    if (idx >= B_*L_*CONVD) return;
    int c = idx % CONVD;
    int t = (idx / CONVD) % L_;
    int b = idx / (CONVD*L_);
    float acc = cb[c];
#pragma unroll
    for (int k = 0; k < K_; k++) {
        int tt = t + k - (K_-1);
        if (tt >= 0)
            acc += (float)proj[((size_t)b*L_ + tt)*DPROJ + DIN + c] * cw[c*K_ + k];
    }
    float s = acc / (1.f + __expf(-acc));
    size_t row = (size_t)b*L_ + t;
    if (c < DIN) u_out[row*DIN + c] = (__bf16)s;
    else bc_out[row*32 + (c - DIN)] = s;
}

// ---------------- B/C normalize + softplus(dt) ----------------
__global__ __launch_bounds__(64) void prep_kernel(
    const float* __restrict__ bc, const __bf16* __restrict__ proj,
    const float* __restrict__ dt_bias,
    float* __restrict__ Bn, float* __restrict__ Cn, float* __restrict__ dtv)
{
    int row = blockIdx.x;
    int tid = threadIdx.x;
    if (tid < 32) {
        float v = bc[(size_t)row*32 + tid];
        float ss = v*v;
        ss += __shfl_xor(ss, 1, 16);
        ss += __shfl_xor(ss, 2, 16);
        ss += __shfl_xor(ss, 4, 16);
        ss += __shfl_xor(ss, 8, 16);
        float nv = v * rsqrtf(ss + 1e-6f);
        if (tid < 16) Bn[(size_t)row*16 + tid] = nv;
        else Cn[(size_t)row*16 + (tid-16)] = nv;
    } else {
        int h = tid - 32;
        float xv = (float)proj[(size_t)row*DPROJ + 2*DIN + 2*N_ + h] + dt_bias[h];
        float sp = (xv > 20.f) ? xv : log1pf(__expf(xv));
        dtv[(size_t)row*32 + h] = sp;
    }
}

// ---------------- sequential SSM scan ----------------
// grid: B_*H_*4 blocks, 64 threads. lane -> (p_local = lane>>2, n-quad = lane&3)
__global__ __launch_bounds__(64) void scan_kernel(
    const float* __restrict__ dtv, const float* __restrict__ Bn,
    const float* __restrict__ Cn, const __bf16* __restrict__ u,
    const __bf16* __restrict__ proj, const float* __restrict__ A_param,
    const float* __restrict__ D_skip, __bf16* __restrict__ y2)
{
    int blk = blockIdx.x;
    int pg = blk & 3;
    int h = (blk >> 2) & 31;
    int b = blk >> 7;
    int lane = threadIdx.x;
    int pl = lane >> 2;
    int p = pg*16 + pl;
    int nq = lane & 3;
    int c = h*64 + p;

    float Av[4], z[4] = {0,0,0,0}, y[4] = {0,0,0,0};
#pragma unroll
    for (int j = 0; j < 4; j++) Av[j] = fmaxf(A_param[h*16 + nq*4 + j], 0.f);
    float Dsk = D_skip[h];

    // prefetch t=0
    size_t row0 = (size_t)b*L_;
    float d  = dtv[row0*32 + h];
    float up = (float)u[row0*DIN + c];
    float zg = (float)proj[row0*DPROJ + c];
    float Bv[4], Cv[4];
#pragma unroll
    for (int j = 0; j < 4; j++) {
        Bv[j] = Bn[row0*16 + nq*4 + j];
        Cv[j] = Cn[row0*16 + nq*4 + j];
    }

    for (int t = 0; t < L_; t++) {
        // prefetch t+1
        float dN = 0.f, upN = 0.f, zgN = 0.f, BvN[4] = {0,0,0,0}, CvN[4] = {0,0,0,0};
        if (t + 1 < L_) {
            size_t rn = (size_t)b*L_ + t + 1;
            dN  = dtv[rn*32 + h];
            upN = (float)u[rn*DIN + c];
            zgN = (float)proj[rn*DPROJ + c];
#pragma unroll
            for (int j = 0; j < 4; j++) {
                BvN[j] = Bn[rn*16 + nq*4 + j];
                CvN[j] = Cn[rn*16 + nq*4 + j];
            }
        }

        float d2 = d*d;
        float s = 0.f;
#pragma unroll
        for (int j = 0; j < 4; j++) {
            float Bu = up * Bv[j];
            float num = z[j] + d*(Bu - Av[j]*y[j]);
            float zn = num * __builtin_amdgcn_rcpf(fmaf(d2, Av[j], 1.f));
            z[j] = zn;
            y[j] = fmaf(d, zn, y[j]);
            s = fmaf(y[j], Cv[j], s);
        }
        s += __shfl_xor(s, 1, 64);
        s += __shfl_xor(s, 2, 64);
        if (nq == 0) {
            float sig = __builtin_amdgcn_rcpf(1.f + __expf(-zg));
            size_t row = (size_t)b*L_ + t;
            y2[row*DIN + c] = (__bf16)((s + Dsk*up) * (zg * sig));
        }

        d = dN; up = upN; zg = zgN;
#pragma unroll
        for (int j = 0; j < 4; j++) { Bv[j] = BvN[j]; Cv[j] = CvN[j]; }
    }
}

extern "C" void kernel_launch(void* const* d_in, const int* in_sizes, int n_in,
                              void* d_out, int out_size, void* d_ws, size_t ws_size,
                              hipStream_t stream) {
    // Inputs fp32 (reference setup_inputs uses jnp.float32; R2 NaN-vs-R3 finite proves it).
    const float* x         = (const float*)d_in[0];
    const float* norm1_w   = (const float*)d_in[1];
    const float* in_proj_w = (const float*)d_in[2];
    const float* conv_w    = (const float*)d_in[3];
    const float* conv_b    = (const float*)d_in[4];
    const float* A_param   = (const float*)d_in[5];
    const float* dt_bias   = (const float*)d_in[6];
    const float* D_skip    = (const float*)d_in[7];
    const float* out_proj_w= (const float*)d_in[8];
    const float* out_proj_b= (const float*)d_in[9];
    const float* norm2_w   = (const float*)d_in[10];
    const float* fc1_w     = (const float*)d_in[11];
    const float* fc1_b     = (const float*)d_in[12];
    const float* fc2_w     = (const float*)d_in[13];
    const float* fc2_b     = (const float*)d_in[14];
    float* out = (float*)d_out;   // fp32 output per reference dtype contract

    // -------- workspace layout with lifetime-based aliasing (~138.4 MB) --------
    char* ws = (char*)d_ws;
    const size_t R0 = 0;
    const size_t R0_SZ = (size_t)M_ROWS*DPROJ*2;               // 68,157,440
    const size_t R1 = R0_SZ;
    const size_t R1_SZ = (size_t)M_ROWS*4*D_*2;                 // 67,108,864
    const size_t R2 = R1 + R1_SZ;                               // 135,266,304

    __bf16* proj   = (__bf16*)(ws + R0);
    float*  x2     = (float*) (ws + R0);                        // aliases proj (dead)
    __bf16* x2n    = (__bf16*)(ws + R0 + (size_t)M_ROWS*D_*4);
    __bf16* xn     = (__bf16*)(ws + R1);
    __bf16* y2     = (__bf16*)(ws + R1);                        // aliases xn (dead)
    __bf16* u_conv = (__bf16*)(ws + R1 + (size_t)M_ROWS*DIN*2);
    __bf16* h1     = (__bf16*)(ws + R1);                        // aliases y2+u_conv (dead)
    float*  bcraw  = (float*)(ws + R2);
    float*  Bn     = (float*)(ws + R2 + (size_t)M_ROWS*32*4);
    float*  Cn     = (float*)(ws + R2 + (size_t)M_ROWS*32*4 + (size_t)M_ROWS*16*4);
    float*  dtv    = (float*)(ws + R2 + (size_t)M_ROWS*32*4 + (size_t)M_ROWS*16*4*2);

    // 1. RMSNorm1 (fp32 x -> bf16 xn)
    rms_kernel<float><<<M_ROWS, 256, 0, stream>>>(x, norm1_w, xn);

    // 2. in_proj GEMM: proj = xn @ in_proj_w^T
    {
        dim3 grid((DPROJ + BN - 1)/BN, M_ROWS/BM);
        gemm_kernel<0, float><<<grid, 256, 0, stream>>>(xn, in_proj_w, proj, nullptr, nullptr,
                                                        M_ROWS, DPROJ, D_);
    }

    // 3. conv + silu
    {
        int total = B_*L_*CONVD;
        conv_kernel<<<(total + 255)/256, 256, 0, stream>>>(proj, conv_w, conv_b, u_conv, bcraw);
    }

    // 4. B/C normalize + dt softplus
    prep_kernel<<<M_ROWS, 64, 0, stream>>>(bcraw, proj, dt_bias, Bn, Cn, dtv);

    // 5. scan (fused D_skip*u + silu(zgate) epilogue) -> y2
    scan_kernel<<<B_*H_*4, 64, 0, stream>>>(dtv, Bn, Cn, u_conv, proj, A_param, D_skip, y2);

    // 6. out_proj GEMM + bias + residual(x fp32) -> x2 (fp32, overwrites dead proj)
    {
        dim3 grid((D_ + BN - 1)/BN, M_ROWS/BM);
        gemm_kernel<2, float><<<grid, 256, 0, stream>>>(y2, out_proj_w, x2, out_proj_b, x,
                                                        M_ROWS, D_, DIN);
    }

    // 7. RMSNorm2
    rms_kernel<float><<<M_ROWS, 256, 0, stream>>>(x2, norm2_w, x2n);

    // 8. fc1 GEMM + bias + gelu -> h1 (overwrites dead y2/u_conv)
    {
        dim3 grid((4*D_ + BN - 1)/BN, M_ROWS/BM);
        gemm_kernel<3, float><<<grid, 256, 0, stream>>>(x2n, fc1_w, h1, fc1_b, nullptr,
                                                        M_ROWS, 4*D_, D_);
    }

    // 9. fc2 GEMM + bias + residual(x2) -> out (fp32)
    {
        dim3 grid((D_ + BN - 1)/BN, M_ROWS/BM);
        gemm_kernel<4, float><<<grid, 256, 0, stream>>>(h1, fc2_w, out, fc2_b, x2,
                                                        M_ROWS, D_, 4*D_);
    }
}

// Round 5
// 1254.674 us; speedup vs baseline: 2.0155x; 2.0155x over previous
//
#include <hip/hip_runtime.h>
#include <hip/hip_bf16.h>
#include <math.h>

#define B_ 2
#define L_ 4096
#define D_ 1024
#define DIN 2048
#define DPROJ 4160
#define CONVD 2080
#define H_ 32
#define P_ 64
#define N_ 16
#define K_ 4
#define M_ROWS (B_*L_)

// chunked scan: NC chunks of CH steps
#define NC 64
#define CH 64

typedef __bf16 bf16_8 __attribute__((ext_vector_type(8)));
typedef float f32x4 __attribute__((ext_vector_type(4)));

// ---------------- RMSNorm (fp32 in, bf16 out) ----------------
template<typename TI>
__global__ __launch_bounds__(256) void rms_kernel(const TI* __restrict__ x,
        const float* __restrict__ w, __bf16* __restrict__ out) {
    int row = blockIdx.x;
    int tid = threadIdx.x;
    const TI* xr = x + (size_t)row * D_;
    float v[4];
    float ss = 0.f;
#pragma unroll
    for (int i = 0; i < 4; i++) {
        v[i] = (float)xr[tid*4 + i];
        ss += v[i]*v[i];
    }
#pragma unroll
    for (int off = 32; off >= 1; off >>= 1) ss += __shfl_xor(ss, off, 64);
    __shared__ float sred[4];
    int wave = tid >> 6;
    if ((tid & 63) == 0) sred[wave] = ss;
    __syncthreads();
    ss = sred[0] + sred[1] + sred[2] + sred[3];
    float scale = rsqrtf(ss * (1.f/(float)D_) + 1e-6f);
#pragma unroll
    for (int i = 0; i < 4; i++)
        out[(size_t)row*D_ + tid*4 + i] = (__bf16)(v[i] * scale * w[tid*4 + i]);
}

// ---------------- GEMM: C = A(MxK,bf16) @ W(NxK,fp32->bf16)^T ----------------
#define BM 128
#define BN 128
#define BK 32
#define BKP 40

template<int EPI, typename TW>
__global__ __launch_bounds__(256) void gemm_kernel(
    const __bf16* __restrict__ A, const TW* __restrict__ W,
    void* __restrict__ Cout, const float* __restrict__ bias,
    const float* __restrict__ resid, int M, int N, int K)
{
    __shared__ __attribute__((aligned(16))) __bf16 As[BM][BKP];
    __shared__ __attribute__((aligned(16))) __bf16 Bs[BN][BKP];
    int tid = threadIdx.x;
    int lane = tid & 63, wave = tid >> 6;
    int wm = wave >> 1, wn = wave & 1;
    int quad = lane >> 4, l16 = lane & 15;
    int bm0 = blockIdx.y * BM, bn0 = blockIdx.x * BN;

    f32x4 acc[4][4] = {};

    for (int kk = 0; kk < K; kk += BK) {
#pragma unroll
        for (int c = 0; c < 2; c++) {
            int chunk = tid + c*256;
            int row = chunk >> 2;
            int col = (chunk & 3) << 3;
            *(uint4*)&As[row][col] = *(const uint4*)(A + (size_t)(bm0+row)*K + kk + col);
            int nr = bn0 + row;
            if constexpr (sizeof(TW) == 2) {
                uint4 bv = make_uint4(0u,0u,0u,0u);
                if (nr < N) bv = *(const uint4*)((const __bf16*)W + (size_t)nr*K + kk + col);
                *(uint4*)&Bs[row][col] = bv;
            } else {
                bf16_8 bv;
#pragma unroll
                for (int q = 0; q < 8; q++) bv[q] = (__bf16)0.f;
                if (nr < N) {
                    const float* wp = (const float*)W + (size_t)nr*K + kk + col;
                    float4 f0 = *(const float4*)wp;
                    float4 f1 = *(const float4*)(wp + 4);
                    bv[0]=(__bf16)f0.x; bv[1]=(__bf16)f0.y; bv[2]=(__bf16)f0.z; bv[3]=(__bf16)f0.w;
                    bv[4]=(__bf16)f1.x; bv[5]=(__bf16)f1.y; bv[6]=(__bf16)f1.z; bv[7]=(__bf16)f1.w;
                }
                *(bf16_8*)&Bs[row][col] = bv;
            }
        }
        __syncthreads();
        bf16_8 af[4], bfr[4];
#pragma unroll
        for (int i = 0; i < 4; i++) {
            af[i]  = *(const bf16_8*)&As[wm*64 + i*16 + l16][quad*8];
            bfr[i] = *(const bf16_8*)&Bs[wn*64 + i*16 + l16][quad*8];
        }
#pragma unroll
        for (int mi = 0; mi < 4; mi++)
#pragma unroll
            for (int ni = 0; ni < 4; ni++)
                acc[mi][ni] = __builtin_amdgcn_mfma_f32_16x16x32_bf16(af[mi], bfr[ni], acc[mi][ni], 0, 0, 0);
        __syncthreads();
    }

#pragma unroll
    for (int mi = 0; mi < 4; mi++) {
        int mbase = bm0 + wm*64 + mi*16 + quad*4;
#pragma unroll
        for (int ni = 0; ni < 4; ni++) {
            int n = bn0 + wn*64 + ni*16 + l16;
            if (n < N) {
#pragma unroll
                for (int r = 0; r < 4; r++) {
                    size_t idx = (size_t)(mbase + r)*N + n;
                    float v = acc[mi][ni][r];
                    if constexpr (EPI == 0) {
                        ((__bf16*)Cout)[idx] = (__bf16)v;
                    } else if constexpr (EPI == 2) {
                        v += bias[n] + resid[idx];
                        ((float*)Cout)[idx] = v;
                    } else if constexpr (EPI == 3) {
                        v += bias[n];
                        float g = 0.5f*v*(1.f + tanhf(0.7978845608f*(v + 0.044715f*v*v*v)));
                        ((__bf16*)Cout)[idx] = (__bf16)g;
                    } else if constexpr (EPI == 4) {
                        v += bias[n] + resid[idx];
                        ((float*)Cout)[idx] = v;   // final output is fp32
                    }
                }
            }
        }
    }
}

// ---------------- depthwise causal conv (K=4) + SiLU ----------------
__global__ __launch_bounds__(256) void conv_kernel(
    const __bf16* __restrict__ proj, const float* __restrict__ cw,
    const float* __restrict__ cb, __bf16* __restrict__ u_out,
    float* __restrict__ bc_out)
{
    int idx = blockIdx.x*256 + threadIdx.x;
    if (idx >= B_*L_*CONVD) return;
    int c = idx % CONVD;
    int t = (idx / CONVD) % L_;
    int b = idx / (CONVD*L_);
    float acc = cb[c];
#pragma unroll
    for (int k = 0; k < K_; k++) {
        int tt = t + k - (K_-1);
        if (tt >= 0)
            acc += (float)proj[((size_t)b*L_ + tt)*DPROJ + DIN + c] * cw[c*K_ + k];
    }
    float s = acc / (1.f + __expf(-acc));
    size_t row = (size_t)b*L_ + t;
    if (c < DIN) u_out[row*DIN + c] = (__bf16)s;
    else bc_out[row*32 + (c - DIN)] = s;
}

// ---------------- B/C normalize + softplus(dt) ----------------
__global__ __launch_bounds__(64) void prep_kernel(
    const float* __restrict__ bc, const __bf16* __restrict__ proj,
    const float* __restrict__ dt_bias,
    float* __restrict__ Bn, float* __restrict__ Cn, float* __restrict__ dtv)
{
    int row = blockIdx.x;
    int tid = threadIdx.x;
    if (tid < 32) {
        float v = bc[(size_t)row*32 + tid];
        float ss = v*v;
        ss += __shfl_xor(ss, 1, 16);
        ss += __shfl_xor(ss, 2, 16);
        ss += __shfl_xor(ss, 4, 16);
        ss += __shfl_xor(ss, 8, 16);
        float nv = v * rsqrtf(ss + 1e-6f);
        if (tid < 16) Bn[(size_t)row*16 + tid] = nv;
        else Cn[(size_t)row*16 + (tid-16)] = nv;
    } else {
        int h = tid - 32;
        float xv = (float)proj[(size_t)row*DPROJ + 2*DIN + 2*N_ + h] + dt_bias[h];
        float sp = (xv > 20.f) ? xv : log1pf(__expf(xv));
        dtv[(size_t)row*32 + h] = sp;
    }
}

// ================= chunked parallel scan =================
// Recurrence per (b,h,p,n):  s_t = M_t s_{t-1} + c_t,  s = [z;y]
//   r = 1/(1+d^2 A);  M = r*[[1, -dA],[d, 1]];  c = d*r*B*u*[1; d]
// Phase 1: per chunk, run from zero state -> v; compose P = prod(M).
// Phase 2: per (b,h), sequential over chunks: write s_start, s = P s + v (in place over v).
// Phase 3: per chunk, run from corrected start, emit output.

// block: ((b*32+h)*4 + pg)*NC + c ; lane: pl=lane>>2 (16 p), nq=lane&3 (4 n-quads)
__global__ __launch_bounds__(64) void scan_phase1(
    const float* __restrict__ dtv, const float* __restrict__ Bn,
    const __bf16* __restrict__ u, const float* __restrict__ A_param,
    float* __restrict__ vbuf, float* __restrict__ Mprod)
{
    int blk = blockIdx.x;
    int c  = blk & (NC-1);
    int pg = (blk >> 6) & 3;
    int h  = (blk >> 8) & 31;
    int b  = blk >> 13;
    int lane = threadIdx.x;
    int pl = lane >> 2, nq = lane & 3;
    int p = pg*16 + pl;
    int ch = h*64 + p;
    int bh = b*32 + h;

    float Av[4];
#pragma unroll
    for (int j = 0; j < 4; j++) Av[j] = fmaxf(A_param[h*16 + nq*4 + j], 0.f);

    float z[4] = {}, y[4] = {};
    float P00[4], P01[4], P10[4], P11[4];
#pragma unroll
    for (int j = 0; j < 4; j++) { P00[j]=1.f; P01[j]=0.f; P10[j]=0.f; P11[j]=1.f; }

    size_t r0 = (size_t)b*L_ + (size_t)c*CH;
    float d  = dtv[r0*32 + h];
    float4 Bv = *(const float4*)&Bn[r0*16 + nq*4];
    float up = (float)u[r0*DIN + ch];

    for (int tt = 0; tt < CH; tt++) {
        float dN = 0.f, upN = 0.f; float4 BvN = make_float4(0,0,0,0);
        if (tt + 1 < CH) {
            size_t rn = r0 + tt + 1;
            dN  = dtv[rn*32 + h];
            BvN = *(const float4*)&Bn[rn*16 + nq*4];
            upN = (float)u[rn*DIN + ch];
        }
        float Bvj[4] = {Bv.x, Bv.y, Bv.z, Bv.w};
#pragma unroll
        for (int j = 0; j < 4; j++) {
            float rc = __builtin_amdgcn_rcpf(fmaf(d*d, Av[j], 1.f));
            float zn = (z[j] + d*(up*Bvj[j] - Av[j]*y[j])) * rc;
            z[j] = zn;
            y[j] = fmaf(d, zn, y[j]);
            float da = d*Av[j];
            float n00 = rc*fmaf(-da, P10[j], P00[j]);
            float n01 = rc*fmaf(-da, P11[j], P01[j]);
            float n10 = rc*fmaf(d, P00[j], P10[j]);
            float n11 = rc*fmaf(d, P01[j], P11[j]);
            P00[j]=n00; P01[j]=n01; P10[j]=n10; P11[j]=n11;
        }
        d = dN; up = upN; Bv = BvN;
    }

    size_t vb = ((size_t)bh*NC + c)*16;
#pragma unroll
    for (int j = 0; j < 4; j++) {
        int n = nq*4 + j;
        size_t vi = ((vb + n)*64 + p)*2;
        vbuf[vi]   = z[j];
        vbuf[vi+1] = y[j];
    }
    if (pl == 0) {
#pragma unroll
        for (int j = 0; j < 4; j++) {
            int n = nq*4 + j;
            size_t mi = (((size_t)bh*NC + c)*16 + n)*4;
            Mprod[mi+0]=P00[j]; Mprod[mi+1]=P01[j]; Mprod[mi+2]=P10[j]; Mprod[mi+3]=P11[j];
        }
    }
}

// 64 blocks (b*32+h), 64 lanes = p. In-place: vbuf[c] := start state of chunk c.
__global__ __launch_bounds__(64) void scan_phase2(
    float* __restrict__ vbuf, const float* __restrict__ Mprod)
{
    int bh = blockIdx.x;
    int p = threadIdx.x;
    float z[16] = {}, y[16] = {};
    for (int c = 0; c < NC; c++) {
        size_t mb = ((size_t)bh*NC + c)*16*4;
        size_t vb = ((size_t)bh*NC + c)*16;
        float m0[16], m1[16], m2[16], m3[16], vz[16], vy[16];
#pragma unroll
        for (int n = 0; n < 16; n++) {
            float4 mm = *(const float4*)&Mprod[mb + n*4];
            m0[n]=mm.x; m1[n]=mm.y; m2[n]=mm.z; m3[n]=mm.w;
            size_t vi = ((vb + n)*64 + p)*2;
            vz[n] = vbuf[vi]; vy[n] = vbuf[vi+1];
        }
#pragma unroll
        for (int n = 0; n < 16; n++) {
            size_t vi = ((vb + n)*64 + p)*2;
            vbuf[vi]   = z[n];
            vbuf[vi+1] = y[n];
        }
#pragma unroll
        for (int n = 0; n < 16; n++) {
            float zn = m0[n]*z[n] + m1[n]*y[n] + vz[n];
            float yn = m2[n]*z[n] + m3[n]*y[n] + vy[n];
            z[n] = zn; y[n] = yn;
        }
    }
}

__global__ __launch_bounds__(64) void scan_phase3(
    const float* __restrict__ dtv, const float* __restrict__ Bn,
    const float* __restrict__ Cn, const __bf16* __restrict__ u,
    const __bf16* __restrict__ proj, const float* __restrict__ A_param,
    const float* __restrict__ D_skip, const float* __restrict__ vbuf,
    __bf16* __restrict__ y2)
{
    int blk = blockIdx.x;
    int c  = blk & (NC-1);
    int pg = (blk >> 6) & 3;
    int h  = (blk >> 8) & 31;
    int b  = blk >> 13;
    int lane = threadIdx.x;
    int pl = lane >> 2, nq = lane & 3;
    int p = pg*16 + pl;
    int ch = h*64 + p;
    int bh = b*32 + h;

    float Av[4];
#pragma unroll
    for (int j = 0; j < 4; j++) Av[j] = fmaxf(A_param[h*16 + nq*4 + j], 0.f);
    float Dsk = D_skip[h];

    float z[4], y[4];
    size_t vb = ((size_t)bh*NC + c)*16;
#pragma unroll
    for (int j = 0; j < 4; j++) {
        int n = nq*4 + j;
        size_t vi = ((vb + n)*64 + p)*2;
        z[j] = vbuf[vi];
        y[j] = vbuf[vi+1];
    }

    size_t r0 = (size_t)b*L_ + (size_t)c*CH;
    float d  = dtv[r0*32 + h];
    float4 Bv = *(const float4*)&Bn[r0*16 + nq*4];
    float4 Cv = *(const float4*)&Cn[r0*16 + nq*4];
    float up = (float)u[r0*DIN + ch];
    float zg = (float)proj[r0*DPROJ + ch];

    for (int tt = 0; tt < CH; tt++) {
        float dN = 0.f, upN = 0.f, zgN = 0.f;
        float4 BvN = make_float4(0,0,0,0), CvN = make_float4(0,0,0,0);
        if (tt + 1 < CH) {
            size_t rn = r0 + tt + 1;
            dN  = dtv[rn*32 + h];
            BvN = *(const float4*)&Bn[rn*16 + nq*4];
            CvN = *(const float4*)&Cn[rn*16 + nq*4];
            upN = (float)u[rn*DIN + ch];
            zgN = (float)proj[rn*DPROJ + ch];
        }
        float Bvj[4] = {Bv.x, Bv.y, Bv.z, Bv.w};
        float Cvj[4] = {Cv.x, Cv.y, Cv.z, Cv.w};
        float s = 0.f;
#pragma unroll
        for (int j = 0; j < 4; j++) {
            float rc = __builtin_amdgcn_rcpf(fmaf(d*d, Av[j], 1.f));
            float zn = (z[j] + d*(up*Bvj[j] - Av[j]*y[j])) * rc;
            z[j] = zn;
            y[j] = fmaf(d, zn, y[j]);
            s = fmaf(y[j], Cvj[j], s);
        }
        s += __shfl_xor(s, 1, 64);
        s += __shfl_xor(s, 2, 64);
        if (nq == 0) {
            float sig = __builtin_amdgcn_rcpf(1.f + __expf(-zg));
            y2[(r0 + tt)*DIN + ch] = (__bf16)((s + Dsk*up) * (zg * sig));
        }
        d = dN; up = upN; zg = zgN; Bv = BvN; Cv = CvN;
    }
}

extern "C" void kernel_launch(void* const* d_in, const int* in_sizes, int n_in,
                              void* d_out, int out_size, void* d_ws, size_t ws_size,
                              hipStream_t stream) {
    const float* x         = (const float*)d_in[0];
    const float* norm1_w   = (const float*)d_in[1];
    const float* in_proj_w = (const float*)d_in[2];
    const float* conv_w    = (const float*)d_in[3];
    const float* conv_b    = (const float*)d_in[4];
    const float* A_param   = (const float*)d_in[5];
    const float* dt_bias   = (const float*)d_in[6];
    const float* D_skip    = (const float*)d_in[7];
    const float* out_proj_w= (const float*)d_in[8];
    const float* out_proj_b= (const float*)d_in[9];
    const float* norm2_w   = (const float*)d_in[10];
    const float* fc1_w     = (const float*)d_in[11];
    const float* fc1_b     = (const float*)d_in[12];
    const float* fc2_w     = (const float*)d_in[13];
    const float* fc2_b     = (const float*)d_in[14];
    float* out = (float*)d_out;

    // -------- workspace layout with lifetime-based aliasing (~139.5 MB) --------
    char* ws = (char*)d_ws;
    const size_t R0 = 0;
    const size_t R0_SZ = (size_t)M_ROWS*DPROJ*2;               // 68,157,440
    const size_t R1 = R0_SZ;
    const size_t R1_SZ = (size_t)M_ROWS*4*D_*2;                 // 67,108,864
    const size_t R2 = R1 + R1_SZ;                               // 135,266,304

    __bf16* proj   = (__bf16*)(ws + R0);
    float*  x2     = (float*) (ws + R0);                        // aliases proj (dead)
    __bf16* x2n    = (__bf16*)(ws + R0 + (size_t)M_ROWS*D_*4);
    __bf16* xn     = (__bf16*)(ws + R1);
    __bf16* y2     = (__bf16*)(ws + R1);                        // aliases xn (dead)
    __bf16* u_conv = (__bf16*)(ws + R1 + (size_t)M_ROWS*DIN*2);
    __bf16* h1     = (__bf16*)(ws + R1);                        // aliases y2+u_conv (dead)
    float*  bcraw  = (float*)(ws + R2);
    float*  Bn     = (float*)(ws + R2 + (size_t)M_ROWS*32*4);
    float*  Cn     = (float*)(ws + R2 + (size_t)M_ROWS*32*4 + (size_t)M_ROWS*16*4);
    float*  dtv    = (float*)(ws + R2 + (size_t)M_ROWS*32*4 + (size_t)M_ROWS*16*4*2);
    float*  Mprod  = (float*)(ws + R2 + (size_t)M_ROWS*32*4*2 + (size_t)M_ROWS*16*4*2); // +1 MB

    // vbuf (chunk states): exactly out_size*4 bytes = 33,554,432 -> use d_out as scratch;
    // fully overwritten by the final fc2 GEMM on the same stream.
    float* vbuf = (float*)d_out;

    // 1. RMSNorm1 (fp32 x -> bf16 xn)
    rms_kernel<float><<<M_ROWS, 256, 0, stream>>>(x, norm1_w, xn);

    // 2. in_proj GEMM: proj = xn @ in_proj_w^T
    {
        dim3 grid((DPROJ + BN - 1)/BN, M_ROWS/BM);
        gemm_kernel<0, float><<<grid, 256, 0, stream>>>(xn, in_proj_w, proj, nullptr, nullptr,
                                                        M_ROWS, DPROJ, D_);
    }

    // 3. conv + silu
    {
        int total = B_*L_*CONVD;
        conv_kernel<<<(total + 255)/256, 256, 0, stream>>>(proj, conv_w, conv_b, u_conv, bcraw);
    }

    // 4. B/C normalize + dt softplus
    prep_kernel<<<M_ROWS, 64, 0, stream>>>(bcraw, proj, dt_bias, Bn, Cn, dtv);

    // 5. chunked scan
    scan_phase1<<<B_*H_*4*NC, 64, 0, stream>>>(dtv, Bn, u_conv, A_param, vbuf, Mprod);
    scan_phase2<<<B_*H_, 64, 0, stream>>>(vbuf, Mprod);
    scan_phase3<<<B_*H_*4*NC, 64, 0, stream>>>(dtv, Bn, Cn, u_conv, proj, A_param, D_skip,
                                               vbuf, y2);

    // 6. out_proj GEMM + bias + residual(x fp32) -> x2 (fp32, overwrites dead proj)
    {
        dim3 grid((D_ + BN - 1)/BN, M_ROWS/BM);
        gemm_kernel<2, float><<<grid, 256, 0, stream>>>(y2, out_proj_w, x2, out_proj_b, x,
                                                        M_ROWS, D_, DIN);
    }

    // 7. RMSNorm2
    rms_kernel<float><<<M_ROWS, 256, 0, stream>>>(x2, norm2_w, x2n);

    // 8. fc1 GEMM + bias + gelu -> h1 (overwrites dead y2/u_conv)
    {
        dim3 grid((4*D_ + BN - 1)/BN, M_ROWS/BM);
        gemm_kernel<3, float><<<grid, 256, 0, stream>>>(x2n, fc1_w, h1, fc1_b, nullptr,
                                                        M_ROWS, 4*D_, D_);
    }

    // 9. fc2 GEMM + bias + residual(x2) -> out (fp32)
    {
        dim3 grid((D_ + BN - 1)/BN, M_ROWS/BM);
        gemm_kernel<4, float><<<grid, 256, 0, stream>>>(h1, fc2_w, out, fc2_b, x2,
                                                        M_ROWS, D_, 4*D_);
    }
}

// Round 6
// 867.754 us; speedup vs baseline: 2.9142x; 1.4459x over previous
//
#include <hip/hip_runtime.h>
#include <hip/hip_bf16.h>
#include <math.h>

#define B_ 2
#define L_ 4096
#define D_ 1024
#define DIN 2048
#define DPROJ 4160
#define CONVD 2080
#define H_ 32
#define P_ 64
#define N_ 16
#define K_ 4
#define M_ROWS (B_*L_)

// chunked scan: NC chunks of CH steps
#define NC 64
#define CH 64

typedef __bf16 bf16_8 __attribute__((ext_vector_type(8)));
typedef float f32x4 __attribute__((ext_vector_type(4)));

// async global->LDS, 16 B per lane; LDS dest = wave-uniform base + lane*16
__device__ __forceinline__ void gload_lds16(const void* g, void* l) {
    __builtin_amdgcn_global_load_lds(
        (const __attribute__((address_space(1))) unsigned int*)g,
        (__attribute__((address_space(3))) unsigned int*)l, 16, 0, 0);
}

// ---------------- fp32 -> bf16 weight conversion ----------------
__global__ __launch_bounds__(256) void cvt_kernel(const float* __restrict__ src,
        __bf16* __restrict__ dst, int n) {
    int i = (blockIdx.x*256 + threadIdx.x)*8;
    if (i < n) {
        float4 f0 = *(const float4*)(src + i);
        float4 f1 = *(const float4*)(src + i + 4);
        bf16_8 o;
        o[0]=(__bf16)f0.x; o[1]=(__bf16)f0.y; o[2]=(__bf16)f0.z; o[3]=(__bf16)f0.w;
        o[4]=(__bf16)f1.x; o[5]=(__bf16)f1.y; o[6]=(__bf16)f1.z; o[7]=(__bf16)f1.w;
        *(bf16_8*)(dst + i) = o;
    }
}

// ---------------- RMSNorm (in fp32/fp32, out bf16) ----------------
template<typename TI>
__global__ __launch_bounds__(256) void rms_kernel(const TI* __restrict__ x,
        const float* __restrict__ w, __bf16* __restrict__ out) {
    int row = blockIdx.x;
    int tid = threadIdx.x;
    const TI* xr = x + (size_t)row * D_;
    float v[4];
    float ss = 0.f;
#pragma unroll
    for (int i = 0; i < 4; i++) {
        v[i] = (float)xr[tid*4 + i];
        ss += v[i]*v[i];
    }
#pragma unroll
    for (int off = 32; off >= 1; off >>= 1) ss += __shfl_xor(ss, off, 64);
    __shared__ float sred[4];
    int wave = tid >> 6;
    if ((tid & 63) == 0) sred[wave] = ss;
    __syncthreads();
    ss = sred[0] + sred[1] + sred[2] + sred[3];
    float scale = rsqrtf(ss * (1.f/(float)D_) + 1e-6f);
#pragma unroll
    for (int i = 0; i < 4; i++)
        out[(size_t)row*D_ + tid*4 + i] = (__bf16)(v[i] * scale * w[tid*4 + i]);
}

// ---------------- GEMM: C = A(MxK,bf16) @ W(NxK,bf16)^T, m97-style staging ----
// EPI 0: store bf16 | EPI 2: +bias+resid -> fp32 | EPI 3: gelu(+bias) -> bf16
// EPI 4: +bias+resid -> fp32 (final output)
#define BM 128
#define BN 128
#define BK 32

template<int EPI>
__global__ __launch_bounds__(256) void gemm_kernel(
    const __bf16* __restrict__ A, const __bf16* __restrict__ W,
    void* __restrict__ Cout, const float* __restrict__ bias,
    const float* __restrict__ resid, int M, int N, int K)
{
    // contiguous lane-order layout (required by global_load_lds): row-major [128][32]
    __shared__ __attribute__((aligned(16))) __bf16 As[BM][BK];   // 8 KB
    __shared__ __attribute__((aligned(16))) __bf16 Bs[BN][BK];   // 8 KB
    int tid = threadIdx.x;
    int lane = tid & 63, wave = tid >> 6;
    int wm = wave >> 1, wn = wave & 1;
    int quad = lane >> 4, l16 = lane & 15;
    int bm0 = blockIdx.y * BM, bn0 = blockIdx.x * BN;

    int srow = lane >> 2;   // 0..15 row within 16-row chunk
    int sseg = lane & 3;    // 16 B (8 bf16) segment within 32-col row

    f32x4 acc[4][4] = {};

    for (int kk = 0; kk < K; kk += BK) {
#pragma unroll
        for (int k = 0; k < 2; k++) {
            int c = wave*2 + k;                 // chunk 0..7 (16 rows each)
            int arow = bm0 + c*16 + srow;
            gload_lds16(A + (size_t)arow*K + kk + sseg*8,
                        (char*)&As[0][0] + c*1024);
            int nr = bn0 + c*16 + srow;
            if (nr < N)
                gload_lds16(W + (size_t)nr*K + kk + sseg*8,
                            (char*)&Bs[0][0] + c*1024);
        }
        __syncthreads();
        bf16_8 af[4], bfr[4];
#pragma unroll
        for (int i = 0; i < 4; i++) {
            af[i]  = *(const bf16_8*)&As[wm*64 + i*16 + l16][quad*8];
            bfr[i] = *(const bf16_8*)&Bs[wn*64 + i*16 + l16][quad*8];
        }
#pragma unroll
        for (int mi = 0; mi < 4; mi++)
#pragma unroll
            for (int ni = 0; ni < 4; ni++)
                acc[mi][ni] = __builtin_amdgcn_mfma_f32_16x16x32_bf16(af[mi], bfr[ni], acc[mi][ni], 0, 0, 0);
        __syncthreads();
    }

#pragma unroll
    for (int mi = 0; mi < 4; mi++) {
        int mbase = bm0 + wm*64 + mi*16 + quad*4;
#pragma unroll
        for (int ni = 0; ni < 4; ni++) {
            int n = bn0 + wn*64 + ni*16 + l16;
            if (n < N) {
#pragma unroll
                for (int r = 0; r < 4; r++) {
                    size_t idx = (size_t)(mbase + r)*N + n;
                    float v = acc[mi][ni][r];
                    if constexpr (EPI == 0) {
                        ((__bf16*)Cout)[idx] = (__bf16)v;
                    } else if constexpr (EPI == 2) {
                        v += bias[n] + resid[idx];
                        ((float*)Cout)[idx] = v;
                    } else if constexpr (EPI == 3) {
                        v += bias[n];
                        float g = 0.5f*v*(1.f + tanhf(0.7978845608f*(v + 0.044715f*v*v*v)));
                        ((__bf16*)Cout)[idx] = (__bf16)g;
                    } else if constexpr (EPI == 4) {
                        v += bias[n] + resid[idx];
                        ((float*)Cout)[idx] = v;
                    }
                }
            }
        }
    }
}

// ---------------- depthwise causal conv (K=4) + SiLU ----------------
__global__ __launch_bounds__(256) void conv_kernel(
    const __bf16* __restrict__ proj, const float* __restrict__ cw,
    const float* __restrict__ cb, __bf16* __restrict__ u_out,
    float* __restrict__ bc_out)
{
    int idx = blockIdx.x*256 + threadIdx.x;
    if (idx >= B_*L_*CONVD) return;
    int c = idx % CONVD;
    int t = (idx / CONVD) % L_;
    int b = idx / (CONVD*L_);
    float acc = cb[c];
#pragma unroll
    for (int k = 0; k < K_; k++) {
        int tt = t + k - (K_-1);
        if (tt >= 0)
            acc += (float)proj[((size_t)b*L_ + tt)*DPROJ + DIN + c] * cw[c*K_ + k];
    }
    float s = acc / (1.f + __expf(-acc));
    size_t row = (size_t)b*L_ + t;
    if (c < DIN) u_out[row*DIN + c] = (__bf16)s;
    else bc_out[row*32 + (c - DIN)] = s;
}

// ---------------- B/C normalize + softplus(dt) ----------------
__global__ __launch_bounds__(64) void prep_kernel(
    const float* __restrict__ bc, const __bf16* __restrict__ proj,
    const float* __restrict__ dt_bias,
    float* __restrict__ Bn, float* __restrict__ Cn, float* __restrict__ dtv)
{
    int row = blockIdx.x;
    int tid = threadIdx.x;
    if (tid < 32) {
        float v = bc[(size_t)row*32 + tid];
        float ss = v*v;
        ss += __shfl_xor(ss, 1, 16);
        ss += __shfl_xor(ss, 2, 16);
        ss += __shfl_xor(ss, 4, 16);
        ss += __shfl_xor(ss, 8, 16);
        float nv = v * rsqrtf(ss + 1e-6f);
        if (tid < 16) Bn[(size_t)row*16 + tid] = nv;
        else Cn[(size_t)row*16 + (tid-16)] = nv;
    } else {
        int h = tid - 32;
        float xv = (float)proj[(size_t)row*DPROJ + 2*DIN + 2*N_ + h] + dt_bias[h];
        float sp = (xv > 20.f) ? xv : log1pf(__expf(xv));
        dtv[(size_t)row*32 + h] = sp;
    }
}

// ================= chunked parallel scan (3 phases) =================
__global__ __launch_bounds__(64) void scan_phase1(
    const float* __restrict__ dtv, const float* __restrict__ Bn,
    const __bf16* __restrict__ u, const float* __restrict__ A_param,
    float* __restrict__ vbuf, float* __restrict__ Mprod)
{
    int blk = blockIdx.x;
    int c  = blk & (NC-1);
    int pg = (blk >> 6) & 3;
    int h  = (blk >> 8) & 31;
    int b  = blk >> 13;
    int lane = threadIdx.x;
    int pl = lane >> 2, nq = lane & 3;
    int p = pg*16 + pl;
    int ch = h*64 + p;
    int bh = b*32 + h;

    float Av[4];
#pragma unroll
    for (int j = 0; j < 4; j++) Av[j] = fmaxf(A_param[h*16 + nq*4 + j], 0.f);

    float z[4] = {}, y[4] = {};
    float P00[4], P01[4], P10[4], P11[4];
#pragma unroll
    for (int j = 0; j < 4; j++) { P00[j]=1.f; P01[j]=0.f; P10[j]=0.f; P11[j]=1.f; }

    size_t r0 = (size_t)b*L_ + (size_t)c*CH;
    float d  = dtv[r0*32 + h];
    float4 Bv = *(const float4*)&Bn[r0*16 + nq*4];
    float up = (float)u[r0*DIN + ch];

    for (int tt = 0; tt < CH; tt++) {
        float dN = 0.f, upN = 0.f; float4 BvN = make_float4(0,0,0,0);
        if (tt + 1 < CH) {
            size_t rn = r0 + tt + 1;
            dN  = dtv[rn*32 + h];
            BvN = *(const float4*)&Bn[rn*16 + nq*4];
            upN = (float)u[rn*DIN + ch];
        }
        float Bvj[4] = {Bv.x, Bv.y, Bv.z, Bv.w};
#pragma unroll
        for (int j = 0; j < 4; j++) {
            float rc = __builtin_amdgcn_rcpf(fmaf(d*d, Av[j], 1.f));
            float zn = (z[j] + d*(up*Bvj[j] - Av[j]*y[j])) * rc;
            z[j] = zn;
            y[j] = fmaf(d, zn, y[j]);
            float da = d*Av[j];
            float n00 = rc*fmaf(-da, P10[j], P00[j]);
            float n01 = rc*fmaf(-da, P11[j], P01[j]);
            float n10 = rc*fmaf(d, P00[j], P10[j]);
            float n11 = rc*fmaf(d, P01[j], P11[j]);
            P00[j]=n00; P01[j]=n01; P10[j]=n10; P11[j]=n11;
        }
        d = dN; up = upN; Bv = BvN;
    }

    size_t vb = ((size_t)bh*NC + c)*16;
#pragma unroll
    for (int j = 0; j < 4; j++) {
        int n = nq*4 + j;
        size_t vi = ((vb + n)*64 + p)*2;
        vbuf[vi]   = z[j];
        vbuf[vi+1] = y[j];
    }
    if (pl == 0) {
#pragma unroll
        for (int j = 0; j < 4; j++) {
            int n = nq*4 + j;
            size_t mi = (((size_t)bh*NC + c)*16 + n)*4;
            Mprod[mi+0]=P00[j]; Mprod[mi+1]=P01[j]; Mprod[mi+2]=P10[j]; Mprod[mi+3]=P11[j];
        }
    }
}

__global__ __launch_bounds__(64) void scan_phase2(
    float* __restrict__ vbuf, const float* __restrict__ Mprod)
{
    int bh = blockIdx.x;
    int p = threadIdx.x;
    float z[16] = {}, y[16] = {};
    for (int c = 0; c < NC; c++) {
        size_t mb = ((size_t)bh*NC + c)*16*4;
        size_t vb = ((size_t)bh*NC + c)*16;
        float m0[16], m1[16], m2[16], m3[16], vz[16], vy[16];
#pragma unroll
        for (int n = 0; n < 16; n++) {
            float4 mm = *(const float4*)&Mprod[mb + n*4];
            m0[n]=mm.x; m1[n]=mm.y; m2[n]=mm.z; m3[n]=mm.w;
            size_t vi = ((vb + n)*64 + p)*2;
            vz[n] = vbuf[vi]; vy[n] = vbuf[vi+1];
        }
#pragma unroll
        for (int n = 0; n < 16; n++) {
            size_t vi = ((vb + n)*64 + p)*2;
            vbuf[vi]   = z[n];
            vbuf[vi+1] = y[n];
        }
#pragma unroll
        for (int n = 0; n < 16; n++) {
            float zn = m0[n]*z[n] + m1[n]*y[n] + vz[n];
            float yn = m2[n]*z[n] + m3[n]*y[n] + vy[n];
            z[n] = zn; y[n] = yn;
        }
    }
}

__global__ __launch_bounds__(64) void scan_phase3(
    const float* __restrict__ dtv, const float* __restrict__ Bn,
    const float* __restrict__ Cn, const __bf16* __restrict__ u,
    const __bf16* __restrict__ proj, const float* __restrict__ A_param,
    const float* __restrict__ D_skip, const float* __restrict__ vbuf,
    __bf16* __restrict__ y2)
{
    int blk = blockIdx.x;
    int c  = blk & (NC-1);
    int pg = (blk >> 6) & 3;
    int h  = (blk >> 8) & 31;
    int b  = blk >> 13;
    int lane = threadIdx.x;
    int pl = lane >> 2, nq = lane & 3;
    int p = pg*16 + pl;
    int ch = h*64 + p;
    int bh = b*32 + h;

    float Av[4];
#pragma unroll
    for (int j = 0; j < 4; j++) Av[j] = fmaxf(A_param[h*16 + nq*4 + j], 0.f);
    float Dsk = D_skip[h];

    float z[4], y[4];
    size_t vb = ((size_t)bh*NC + c)*16;
#pragma unroll
    for (int j = 0; j < 4; j++) {
        int n = nq*4 + j;
        size_t vi = ((vb + n)*64 + p)*2;
        z[j] = vbuf[vi];
        y[j] = vbuf[vi+1];
    }

    size_t r0 = (size_t)b*L_ + (size_t)c*CH;
    float d  = dtv[r0*32 + h];
    float4 Bv = *(const float4*)&Bn[r0*16 + nq*4];
    float4 Cv = *(const float4*)&Cn[r0*16 + nq*4];
    float up = (float)u[r0*DIN + ch];
    float zg = (float)proj[r0*DPROJ + ch];

    for (int tt = 0; tt < CH; tt++) {
        float dN = 0.f, upN = 0.f, zgN = 0.f;
        float4 BvN = make_float4(0,0,0,0), CvN = make_float4(0,0,0,0);
        if (tt + 1 < CH) {
            size_t rn = r0 + tt + 1;
            dN  = dtv[rn*32 + h];
            BvN = *(const float4*)&Bn[rn*16 + nq*4];
            CvN = *(const float4*)&Cn[rn*16 + nq*4];
            upN = (float)u[rn*DIN + ch];
            zgN = (float)proj[rn*DPROJ + ch];
        }
        float Bvj[4] = {Bv.x, Bv.y, Bv.z, Bv.w};
        float Cvj[4] = {Cv.x, Cv.y, Cv.z, Cv.w};
        float s = 0.f;
#pragma unroll
        for (int j = 0; j < 4; j++) {
            float rc = __builtin_amdgcn_rcpf(fmaf(d*d, Av[j], 1.f));
            float zn = (z[j] + d*(up*Bvj[j] - Av[j]*y[j])) * rc;
            z[j] = zn;
            y[j] = fmaf(d, zn, y[j]);
            s = fmaf(y[j], Cvj[j], s);
        }
        s += __shfl_xor(s, 1, 64);
        s += __shfl_xor(s, 2, 64);
        if (nq == 0) {
            float sig = __builtin_amdgcn_rcpf(1.f + __expf(-zg));
            y2[(r0 + tt)*DIN + ch] = (__bf16)((s + Dsk*up) * (zg * sig));
        }
        d = dN; up = upN; zg = zgN; Bv = BvN; Cv = CvN;
    }
}

extern "C" void kernel_launch(void* const* d_in, const int* in_sizes, int n_in,
                              void* d_out, int out_size, void* d_ws, size_t ws_size,
                              hipStream_t stream) {
    const float* x         = (const float*)d_in[0];
    const float* norm1_w   = (const float*)d_in[1];
    const float* in_proj_w = (const float*)d_in[2];
    const float* conv_w    = (const float*)d_in[3];
    const float* conv_b    = (const float*)d_in[4];
    const float* A_param   = (const float*)d_in[5];
    const float* dt_bias   = (const float*)d_in[6];
    const float* D_skip    = (const float*)d_in[7];
    const float* out_proj_w= (const float*)d_in[8];
    const float* out_proj_b= (const float*)d_in[9];
    const float* norm2_w   = (const float*)d_in[10];
    const float* fc1_w     = (const float*)d_in[11];
    const float* fc1_b     = (const float*)d_in[12];
    const float* fc2_w     = (const float*)d_in[13];
    const float* fc2_b     = (const float*)d_in[14];
    float* out = (float*)d_out;

    // -------- workspace layout with lifetime-based aliasing (~148 MB) --------
    char* ws = (char*)d_ws;
    const size_t R0 = 0;
    const size_t R0_SZ = (size_t)M_ROWS*DPROJ*2;               // 68,157,440
    const size_t R1 = R0_SZ;
    const size_t R1_SZ = (size_t)M_ROWS*4*D_*2;                 // 67,108,864
    const size_t R2 = R1 + R1_SZ;                               // 135,266,304

    __bf16* proj   = (__bf16*)(ws + R0);
    float*  x2     = (float*) (ws + R0);                        // aliases proj (dead)
    __bf16* x2n    = (__bf16*)(ws + R0 + (size_t)M_ROWS*D_*4);
    __bf16* xn     = (__bf16*)(ws + R1);
    __bf16* y2     = (__bf16*)(ws + R1);                        // aliases xn (dead)
    __bf16* u_conv = (__bf16*)(ws + R1 + (size_t)M_ROWS*DIN*2);
    __bf16* h1     = (__bf16*)(ws + R1);                        // aliases y2+u_conv (dead)
    float*  bcraw  = (float*)(ws + R2);                                       // 1 MB
    float*  Bn     = (float*)(ws + R2 + (size_t)M_ROWS*32*4);                 // 0.5 MB
    float*  Cn     = (float*)(ws + R2 + (size_t)M_ROWS*32*4 + (size_t)M_ROWS*16*4);
    float*  dtv    = (float*)(ws + R2 + (size_t)M_ROWS*32*4 + (size_t)M_ROWS*16*4*2);
    float*  Mprod  = (float*)(ws + R2 + (size_t)M_ROWS*32*4*2 + (size_t)M_ROWS*16*4*2); // 1 MB
    __bf16* Wb     = (__bf16*)(ws + R2 + (size_t)M_ROWS*32*4*2 + (size_t)M_ROWS*16*4*2
                                 + (size_t)64*64*16*4*4);       // 8.52 MB slot, reused per GEMM

    float* vbuf = (float*)d_out;   // scan scratch; fully overwritten by fc2 GEMM

    // 1. RMSNorm1 (fp32 x -> bf16 xn)
    rms_kernel<float><<<M_ROWS, 256, 0, stream>>>(x, norm1_w, xn);

    // 2. in_proj GEMM: proj = xn @ in_proj_w^T
    {
        int n = DPROJ*D_;
        cvt_kernel<<<(n/8 + 255)/256, 256, 0, stream>>>(in_proj_w, Wb, n);
        dim3 grid((DPROJ + BN - 1)/BN, M_ROWS/BM);
        gemm_kernel<0><<<grid, 256, 0, stream>>>(xn, Wb, proj, nullptr, nullptr,
                                                 M_ROWS, DPROJ, D_);
    }

    // 3. conv + silu
    {
        int total = B_*L_*CONVD;
        conv_kernel<<<(total + 255)/256, 256, 0, stream>>>(proj, conv_w, conv_b, u_conv, bcraw);
    }

    // 4. B/C normalize + dt softplus
    prep_kernel<<<M_ROWS, 64, 0, stream>>>(bcraw, proj, dt_bias, Bn, Cn, dtv);

    // 5. chunked scan
    scan_phase1<<<B_*H_*4*NC, 64, 0, stream>>>(dtv, Bn, u_conv, A_param, vbuf, Mprod);
    scan_phase2<<<B_*H_, 64, 0, stream>>>(vbuf, Mprod);
    scan_phase3<<<B_*H_*4*NC, 64, 0, stream>>>(dtv, Bn, Cn, u_conv, proj, A_param, D_skip,
                                               vbuf, y2);

    // 6. out_proj GEMM + bias + residual(x) -> x2 (fp32, overwrites dead proj)
    {
        int n = D_*DIN;
        cvt_kernel<<<(n/8 + 255)/256, 256, 0, stream>>>(out_proj_w, Wb, n);
        dim3 grid((D_ + BN - 1)/BN, M_ROWS/BM);
        gemm_kernel<2><<<grid, 256, 0, stream>>>(y2, Wb, x2, out_proj_b, x, M_ROWS, D_, DIN);
    }

    // 7. RMSNorm2
    rms_kernel<float><<<M_ROWS, 256, 0, stream>>>(x2, norm2_w, x2n);

    // 8. fc1 GEMM + bias + gelu -> h1 (overwrites dead y2/u_conv)
    {
        int n = 4*D_*D_;
        cvt_kernel<<<(n/8 + 255)/256, 256, 0, stream>>>(fc1_w, Wb, n);
        dim3 grid((4*D_ + BN - 1)/BN, M_ROWS/BM);
        gemm_kernel<3><<<grid, 256, 0, stream>>>(x2n, Wb, h1, fc1_b, nullptr, M_ROWS, 4*D_, D_);
    }

    // 9. fc2 GEMM + bias + residual(x2) -> out (fp32)
    {
        int n = D_*4*D_;
        cvt_kernel<<<(n/8 + 255)/256, 256, 0, stream>>>(fc2_w, Wb, n);
        dim3 grid((D_ + BN - 1)/BN, M_ROWS/BM);
        gemm_kernel<4><<<grid, 256, 0, stream>>>(h1, Wb, out, fc2_b, x2, M_ROWS, D_, 4*D_);
    }
}

// Round 7
// 867.470 us; speedup vs baseline: 2.9151x; 1.0003x over previous
//
#include <hip/hip_runtime.h>
#include <hip/hip_bf16.h>
#include <math.h>

#define B_ 2
#define L_ 4096
#define D_ 1024
#define DIN 2048
#define DPROJ 4160
#define CONVD 2080
#define H_ 32
#define P_ 64
#define N_ 16
#define K_ 4
#define M_ROWS (B_*L_)

// chunked scan: NC chunks of CH steps
#define NC 64
#define CH 64

typedef __bf16 bf16_8 __attribute__((ext_vector_type(8)));
typedef float f32x4 __attribute__((ext_vector_type(4)));

// async global->LDS, 16 B per lane; LDS dest = wave-uniform base + lane*16
__device__ __forceinline__ void gload_lds16(const void* g, void* l) {
    __builtin_amdgcn_global_load_lds(
        (const __attribute__((address_space(1))) unsigned int*)g,
        (__attribute__((address_space(3))) unsigned int*)l, 16, 0, 0);
}

// ---------------- fp32 -> bf16 weight conversion ----------------
__global__ __launch_bounds__(256) void cvt_kernel(const float* __restrict__ src,
        __bf16* __restrict__ dst, int n) {
    int i = (blockIdx.x*256 + threadIdx.x)*8;
    if (i < n) {
        float4 f0 = *(const float4*)(src + i);
        float4 f1 = *(const float4*)(src + i + 4);
        bf16_8 o;
        o[0]=(__bf16)f0.x; o[1]=(__bf16)f0.y; o[2]=(__bf16)f0.z; o[3]=(__bf16)f0.w;
        o[4]=(__bf16)f1.x; o[5]=(__bf16)f1.y; o[6]=(__bf16)f1.z; o[7]=(__bf16)f1.w;
        *(bf16_8*)(dst + i) = o;
    }
}

// ---------------- RMSNorm (in fp32, out bf16) ----------------
template<typename TI>
__global__ __launch_bounds__(256) void rms_kernel(const TI* __restrict__ x,
        const float* __restrict__ w, __bf16* __restrict__ out) {
    int row = blockIdx.x;
    int tid = threadIdx.x;
    const TI* xr = x + (size_t)row * D_;
    float v[4];
    float ss = 0.f;
#pragma unroll
    for (int i = 0; i < 4; i++) {
        v[i] = (float)xr[tid*4 + i];
        ss += v[i]*v[i];
    }
#pragma unroll
    for (int off = 32; off >= 1; off >>= 1) ss += __shfl_xor(ss, off, 64);
    __shared__ float sred[4];
    int wave = tid >> 6;
    if ((tid & 63) == 0) sred[wave] = ss;
    __syncthreads();
    ss = sred[0] + sred[1] + sred[2] + sred[3];
    float scale = rsqrtf(ss * (1.f/(float)D_) + 1e-6f);
#pragma unroll
    for (int i = 0; i < 4; i++)
        out[(size_t)row*D_ + tid*4 + i] = (__bf16)(v[i] * scale * w[tid*4 + i]);
}

// ---------------- GEMM: C = A(MxK,bf16) @ W(NxK,bf16)^T ----------------
// grouped rasterization (GROUP_M=8) for L2/L3 W-reuse.
// EPI 0: store bf16 | EPI 2: +bias+resid -> fp32 | EPI 3: gelu(+bias) -> bf16
// EPI 4: +bias+resid -> fp32 (final output)
#define BM 128
#define BN 128
#define BK 32

template<int EPI>
__global__ __launch_bounds__(256) void gemm_kernel(
    const __bf16* __restrict__ A, const __bf16* __restrict__ W,
    void* __restrict__ Cout, const float* __restrict__ bias,
    const float* __restrict__ resid, int M, int N, int K)
{
    __shared__ __attribute__((aligned(16))) __bf16 As[BM][BK];   // 8 KB
    __shared__ __attribute__((aligned(16))) __bf16 Bs[BN][BK];   // 8 KB
    int tid = threadIdx.x;
    int lane = tid & 63, wave = tid >> 6;
    int wm = wave >> 1, wn = wave & 1;
    int quad = lane >> 4, l16 = lane & 15;

    // grouped raster: groups of 8 M-blocks share the N-sweep -> W streamed 1/8 as often
    int num_n = gridDim.x, num_m = gridDim.y;
    int pid = blockIdx.y * num_n + blockIdx.x;
    const int G = 8;
    int gsz = G * num_n;
    int grp = pid / gsz;
    int rem = pid - grp * gsz;
    int first_m = grp * G;
    int gm = (num_m - first_m < G) ? (num_m - first_m) : G;
    int m_idx = first_m + rem % gm;
    int n_idx = rem / gm;
    int bm0 = m_idx * BM, bn0 = n_idx * BN;

    int srow = lane >> 2;   // 0..15 row within 16-row chunk
    int sseg = lane & 3;    // 16 B (8 bf16) segment within 32-col row

    f32x4 acc[4][4] = {};

    for (int kk = 0; kk < K; kk += BK) {
#pragma unroll
        for (int k = 0; k < 2; k++) {
            int c = wave*2 + k;                 // chunk 0..7 (16 rows each)
            int arow = bm0 + c*16 + srow;
            gload_lds16(A + (size_t)arow*K + kk + sseg*8,
                        (char*)&As[0][0] + c*1024);
            int nr = bn0 + c*16 + srow;
            if (nr < N)
                gload_lds16(W + (size_t)nr*K + kk + sseg*8,
                            (char*)&Bs[0][0] + c*1024);
        }
        __syncthreads();
        bf16_8 af[4], bfr[4];
#pragma unroll
        for (int i = 0; i < 4; i++) {
            af[i]  = *(const bf16_8*)&As[wm*64 + i*16 + l16][quad*8];
            bfr[i] = *(const bf16_8*)&Bs[wn*64 + i*16 + l16][quad*8];
        }
#pragma unroll
        for (int mi = 0; mi < 4; mi++)
#pragma unroll
            for (int ni = 0; ni < 4; ni++)
                acc[mi][ni] = __builtin_amdgcn_mfma_f32_16x16x32_bf16(af[mi], bfr[ni], acc[mi][ni], 0, 0, 0);
        __syncthreads();
    }

#pragma unroll
    for (int mi = 0; mi < 4; mi++) {
        int mbase = bm0 + wm*64 + mi*16 + quad*4;
#pragma unroll
        for (int ni = 0; ni < 4; ni++) {
            int n = bn0 + wn*64 + ni*16 + l16;
            if (n < N) {
#pragma unroll
                for (int r = 0; r < 4; r++) {
                    size_t idx = (size_t)(mbase + r)*N + n;
                    float v = acc[mi][ni][r];
                    if constexpr (EPI == 0) {
                        ((__bf16*)Cout)[idx] = (__bf16)v;
                    } else if constexpr (EPI == 2) {
                        v += bias[n] + resid[idx];
                        ((float*)Cout)[idx] = v;
                    } else if constexpr (EPI == 3) {
                        v += bias[n];
                        float g = 0.5f*v*(1.f + tanhf(0.7978845608f*(v + 0.044715f*v*v*v)));
                        ((__bf16*)Cout)[idx] = (__bf16)g;
                    } else if constexpr (EPI == 4) {
                        v += bias[n] + resid[idx];
                        ((float*)Cout)[idx] = v;
                    }
                }
            }
        }
    }
}

// ---------------- depthwise causal conv (K=4) + SiLU ----------------
__global__ __launch_bounds__(256) void conv_kernel(
    const __bf16* __restrict__ proj, const float* __restrict__ cw,
    const float* __restrict__ cb, __bf16* __restrict__ u_out,
    float* __restrict__ bc_out)
{
    int idx = blockIdx.x*256 + threadIdx.x;
    if (idx >= B_*L_*CONVD) return;
    int c = idx % CONVD;
    int t = (idx / CONVD) % L_;
    int b = idx / (CONVD*L_);
    float acc = cb[c];
#pragma unroll
    for (int k = 0; k < K_; k++) {
        int tt = t + k - (K_-1);
        if (tt >= 0)
            acc += (float)proj[((size_t)b*L_ + tt)*DPROJ + DIN + c] * cw[c*K_ + k];
    }
    float s = acc / (1.f + __expf(-acc));
    size_t row = (size_t)b*L_ + t;
    if (c < DIN) u_out[row*DIN + c] = (__bf16)s;
    else bc_out[row*32 + (c - DIN)] = s;
}

// ---------------- B/C normalize + softplus(dt) ----------------
__global__ __launch_bounds__(64) void prep_kernel(
    const float* __restrict__ bc, const __bf16* __restrict__ proj,
    const float* __restrict__ dt_bias,
    float* __restrict__ Bn, float* __restrict__ Cn, float* __restrict__ dtv)
{
    int row = blockIdx.x;
    int tid = threadIdx.x;
    if (tid < 32) {
        float v = bc[(size_t)row*32 + tid];
        float ss = v*v;
        ss += __shfl_xor(ss, 1, 16);
        ss += __shfl_xor(ss, 2, 16);
        ss += __shfl_xor(ss, 4, 16);
        ss += __shfl_xor(ss, 8, 16);
        float nv = v * rsqrtf(ss + 1e-6f);
        if (tid < 16) Bn[(size_t)row*16 + tid] = nv;
        else Cn[(size_t)row*16 + (tid-16)] = nv;
    } else {
        int h = tid - 32;
        float xv = (float)proj[(size_t)row*DPROJ + 2*DIN + 2*N_ + h] + dt_bias[h];
        float sp = (xv > 20.f) ? xv : log1pf(__expf(xv));
        dtv[(size_t)row*32 + h] = sp;
    }
}

// ================= chunked parallel scan (3 phases) =================
__global__ __launch_bounds__(64) void scan_phase1(
    const float* __restrict__ dtv, const float* __restrict__ Bn,
    const __bf16* __restrict__ u, const float* __restrict__ A_param,
    float* __restrict__ vbuf, float* __restrict__ Mprod)
{
    int blk = blockIdx.x;
    int c  = blk & (NC-1);
    int pg = (blk >> 6) & 3;
    int h  = (blk >> 8) & 31;
    int b  = blk >> 13;
    int lane = threadIdx.x;
    int pl = lane >> 2, nq = lane & 3;
    int p = pg*16 + pl;
    int ch = h*64 + p;
    int bh = b*32 + h;

    float Av[4];
#pragma unroll
    for (int j = 0; j < 4; j++) Av[j] = fmaxf(A_param[h*16 + nq*4 + j], 0.f);

    float z[4] = {}, y[4] = {};
    float P00[4], P01[4], P10[4], P11[4];
#pragma unroll
    for (int j = 0; j < 4; j++) { P00[j]=1.f; P01[j]=0.f; P10[j]=0.f; P11[j]=1.f; }

    size_t r0 = (size_t)b*L_ + (size_t)c*CH;

#pragma unroll 4
    for (int tt = 0; tt < CH; tt++) {
        size_t rn = r0 + tt;
        float d  = dtv[rn*32 + h];
        float4 Bv = *(const float4*)&Bn[rn*16 + nq*4];
        float up = (float)u[rn*DIN + ch];
        float Bvj[4] = {Bv.x, Bv.y, Bv.z, Bv.w};
#pragma unroll
        for (int j = 0; j < 4; j++) {
            float rc = __builtin_amdgcn_rcpf(fmaf(d*d, Av[j], 1.f));
            float zn = (z[j] + d*(up*Bvj[j] - Av[j]*y[j])) * rc;
            z[j] = zn;
            y[j] = fmaf(d, zn, y[j]);
            float da = d*Av[j];
            float n00 = rc*fmaf(-da, P10[j], P00[j]);
            float n01 = rc*fmaf(-da, P11[j], P01[j]);
            float n10 = rc*fmaf(d, P00[j], P10[j]);
            float n11 = rc*fmaf(d, P01[j], P11[j]);
            P00[j]=n00; P01[j]=n01; P10[j]=n10; P11[j]=n11;
        }
    }

    size_t vb = ((size_t)bh*NC + c)*16;
#pragma unroll
    for (int j = 0; j < 4; j++) {
        int n = nq*4 + j;
        size_t vi = ((vb + n)*64 + p)*2;
        vbuf[vi]   = z[j];
        vbuf[vi+1] = y[j];
    }
    if (pl == 0) {
#pragma unroll
        for (int j = 0; j < 4; j++) {
            int n = nq*4 + j;
            size_t mi = (((size_t)bh*NC + c)*16 + n)*4;
            Mprod[mi+0]=P00[j]; Mprod[mi+1]=P01[j]; Mprod[mi+2]=P10[j]; Mprod[mi+3]=P11[j];
        }
    }
}

__global__ __launch_bounds__(64) void scan_phase2(
    float* __restrict__ vbuf, const float* __restrict__ Mprod)
{
    int bh = blockIdx.x;
    int p = threadIdx.x;
    float z[16] = {}, y[16] = {};
    for (int c = 0; c < NC; c++) {
        size_t mb = ((size_t)bh*NC + c)*16*4;
        size_t vb = ((size_t)bh*NC + c)*16;
        float m0[16], m1[16], m2[16], m3[16], vz[16], vy[16];
#pragma unroll
        for (int n = 0; n < 16; n++) {
            float4 mm = *(const float4*)&Mprod[mb + n*4];
            m0[n]=mm.x; m1[n]=mm.y; m2[n]=mm.z; m3[n]=mm.w;
            size_t vi = ((vb + n)*64 + p)*2;
            vz[n] = vbuf[vi]; vy[n] = vbuf[vi+1];
        }
#pragma unroll
        for (int n = 0; n < 16; n++) {
            size_t vi = ((vb + n)*64 + p)*2;
            vbuf[vi]   = z[n];
            vbuf[vi+1] = y[n];
        }
#pragma unroll
        for (int n = 0; n < 16; n++) {
            float zn = m0[n]*z[n] + m1[n]*y[n] + vz[n];
            float yn = m2[n]*z[n] + m3[n]*y[n] + vy[n];
            z[n] = zn; y[n] = yn;
        }
    }
}

__global__ __launch_bounds__(64) void scan_phase3(
    const float* __restrict__ dtv, const float* __restrict__ Bn,
    const float* __restrict__ Cn, const __bf16* __restrict__ u,
    const __bf16* __restrict__ proj, const float* __restrict__ A_param,
    const float* __restrict__ D_skip, const float* __restrict__ vbuf,
    __bf16* __restrict__ y2)
{
    int blk = blockIdx.x;
    int c  = blk & (NC-1);
    int pg = (blk >> 6) & 3;
    int h  = (blk >> 8) & 31;
    int b  = blk >> 13;
    int lane = threadIdx.x;
    int pl = lane >> 2, nq = lane & 3;
    int p = pg*16 + pl;
    int ch = h*64 + p;
    int bh = b*32 + h;

    float Av[4];
#pragma unroll
    for (int j = 0; j < 4; j++) Av[j] = fmaxf(A_param[h*16 + nq*4 + j], 0.f);
    float Dsk = D_skip[h];

    float z[4], y[4];
    size_t vb = ((size_t)bh*NC + c)*16;
#pragma unroll
    for (int j = 0; j < 4; j++) {
        int n = nq*4 + j;
        size_t vi = ((vb + n)*64 + p)*2;
        z[j] = vbuf[vi];
        y[j] = vbuf[vi+1];
    }

    size_t r0 = (size_t)b*L_ + (size_t)c*CH;

#pragma unroll 4
    for (int tt = 0; tt < CH; tt++) {
        size_t rn = r0 + tt;
        float d  = dtv[rn*32 + h];
        float4 Bv = *(const float4*)&Bn[rn*16 + nq*4];
        float4 Cv = *(const float4*)&Cn[rn*16 + nq*4];
        float up = (float)u[rn*DIN + ch];
        float zg = (float)proj[rn*DPROJ + ch];
        float Bvj[4] = {Bv.x, Bv.y, Bv.z, Bv.w};
        float Cvj[4] = {Cv.x, Cv.y, Cv.z, Cv.w};
        float s = 0.f;
#pragma unroll
        for (int j = 0; j < 4; j++) {
            float rc = __builtin_amdgcn_rcpf(fmaf(d*d, Av[j], 1.f));
            float zn = (z[j] + d*(up*Bvj[j] - Av[j]*y[j])) * rc;
            z[j] = zn;
            y[j] = fmaf(d, zn, y[j]);
            s = fmaf(y[j], Cvj[j], s);
        }
        s += __shfl_xor(s, 1, 64);
        s += __shfl_xor(s, 2, 64);
        if (nq == 0) {
            float sig = __builtin_amdgcn_rcpf(1.f + __expf(-zg));
            y2[rn*DIN + ch] = (__bf16)((s + Dsk*up) * (zg * sig));
        }
    }
}

extern "C" void kernel_launch(void* const* d_in, const int* in_sizes, int n_in,
                              void* d_out, int out_size, void* d_ws, size_t ws_size,
                              hipStream_t stream) {
    const float* x         = (const float*)d_in[0];
    const float* norm1_w   = (const float*)d_in[1];
    const float* in_proj_w = (const float*)d_in[2];
    const float* conv_w    = (const float*)d_in[3];
    const float* conv_b    = (const float*)d_in[4];
    const float* A_param   = (const float*)d_in[5];
    const float* dt_bias   = (const float*)d_in[6];
    const float* D_skip    = (const float*)d_in[7];
    const float* out_proj_w= (const float*)d_in[8];
    const float* out_proj_b= (const float*)d_in[9];
    const float* norm2_w   = (const float*)d_in[10];
    const float* fc1_w     = (const float*)d_in[11];
    const float* fc1_b     = (const float*)d_in[12];
    const float* fc2_w     = (const float*)d_in[13];
    const float* fc2_b     = (const float*)d_in[14];
    float* out = (float*)d_out;

    // -------- workspace layout with lifetime-based aliasing (~148 MB) --------
    char* ws = (char*)d_ws;
    const size_t R0 = 0;
    const size_t R0_SZ = (size_t)M_ROWS*DPROJ*2;               // 68,157,440
    const size_t R1 = R0_SZ;
    const size_t R1_SZ = (size_t)M_ROWS*4*D_*2;                 // 67,108,864
    const size_t R2 = R1 + R1_SZ;                               // 135,266,304

    __bf16* proj   = (__bf16*)(ws + R0);
    float*  x2     = (float*) (ws + R0);                        // aliases proj (dead)
    __bf16* x2n    = (__bf16*)(ws + R0 + (size_t)M_ROWS*D_*4);
    __bf16* xn     = (__bf16*)(ws + R1);
    __bf16* y2     = (__bf16*)(ws + R1);                        // aliases xn (dead)
    __bf16* u_conv = (__bf16*)(ws + R1 + (size_t)M_ROWS*DIN*2);
    __bf16* h1     = (__bf16*)(ws + R1);                        // aliases y2+u_conv (dead)
    float*  bcraw  = (float*)(ws + R2);                                       // 1 MB
    float*  Bn     = (float*)(ws + R2 + (size_t)M_ROWS*32*4);                 // 0.5 MB
    float*  Cn     = (float*)(ws + R2 + (size_t)M_ROWS*32*4 + (size_t)M_ROWS*16*4);
    float*  dtv    = (float*)(ws + R2 + (size_t)M_ROWS*32*4 + (size_t)M_ROWS*16*4*2);
    float*  Mprod  = (float*)(ws + R2 + (size_t)M_ROWS*32*4*2 + (size_t)M_ROWS*16*4*2); // 1 MB
    __bf16* Wb     = (__bf16*)(ws + R2 + (size_t)M_ROWS*32*4*2 + (size_t)M_ROWS*16*4*2
                                 + (size_t)64*64*16*4*4);       // 8.52 MB slot, reused per GEMM

    float* vbuf = (float*)d_out;   // scan scratch; fully overwritten by fc2 GEMM

    // 1. RMSNorm1 (fp32 x -> bf16 xn)
    rms_kernel<float><<<M_ROWS, 256, 0, stream>>>(x, norm1_w, xn);

    // 2. in_proj GEMM: proj = xn @ in_proj_w^T
    {
        int n = DPROJ*D_;
        cvt_kernel<<<(n/8 + 255)/256, 256, 0, stream>>>(in_proj_w, Wb, n);
        dim3 grid((DPROJ + BN - 1)/BN, M_ROWS/BM);
        gemm_kernel<0><<<grid, 256, 0, stream>>>(xn, Wb, proj, nullptr, nullptr,
                                                 M_ROWS, DPROJ, D_);
    }

    // 3. conv + silu
    {
        int total = B_*L_*CONVD;
        conv_kernel<<<(total + 255)/256, 256, 0, stream>>>(proj, conv_w, conv_b, u_conv, bcraw);
    }

    // 4. B/C normalize + dt softplus
    prep_kernel<<<M_ROWS, 64, 0, stream>>>(bcraw, proj, dt_bias, Bn, Cn, dtv);

    // 5. chunked scan
    scan_phase1<<<B_*H_*4*NC, 64, 0, stream>>>(dtv, Bn, u_conv, A_param, vbuf, Mprod);
    scan_phase2<<<B_*H_, 64, 0, stream>>>(vbuf, Mprod);
    scan_phase3<<<B_*H_*4*NC, 64, 0, stream>>>(dtv, Bn, Cn, u_conv, proj, A_param, D_skip,
                                               vbuf, y2);

    // 6. out_proj GEMM + bias + residual(x) -> x2 (fp32, overwrites dead proj)
    {
        int n = D_*DIN;
        cvt_kernel<<<(n/8 + 255)/256, 256, 0, stream>>>(out_proj_w, Wb, n);
        dim3 grid((D_ + BN - 1)/BN, M_ROWS/BM);
        gemm_kernel<2><<<grid, 256, 0, stream>>>(y2, Wb, x2, out_proj_b, x, M_ROWS, D_, DIN);
    }

    // 7. RMSNorm2
    rms_kernel<float><<<M_ROWS, 256, 0, stream>>>(x2, norm2_w, x2n);

    // 8. fc1 GEMM + bias + gelu -> h1 (overwrites dead y2/u_conv)
    {
        int n = 4*D_*D_;
        cvt_kernel<<<(n/8 + 255)/256, 256, 0, stream>>>(fc1_w, Wb, n);
        dim3 grid((4*D_ + BN - 1)/BN, M_ROWS/BM);
        gemm_kernel<3><<<grid, 256, 0, stream>>>(x2n, Wb, h1, fc1_b, nullptr, M_ROWS, 4*D_, D_);
    }

    // 9. fc2 GEMM + bias + residual(x2) -> out (fp32)
    {
        int n = D_*4*D_;
        cvt_kernel<<<(n/8 + 255)/256, 256, 0, stream>>>(fc2_w, Wb, n);
        dim3 grid((D_ + BN - 1)/BN, M_ROWS/BM);
        gemm_kernel<4><<<grid, 256, 0, stream>>>(h1, Wb, out, fc2_b, x2, M_ROWS, D_, 4*D_);
    }
}